// Round 3
// baseline (681.059 us; speedup 1.0000x reference)
//
#include <hip/hip_runtime.h>
#include <hip/hip_bf16.h>

// Problem constants
#define T_STEPS 15
#define CIN     40
#define H_IN    160
#define W_IN    300
#define COUT    50
#define OH      157   // 160-4+1
#define OW      295   // 300-6+1
#define PH      52    // OH/3
#define PW      98    // OW/3
#define THRESH  15.0f

// Implicit-GEMM geometry
#define K2      160   // k2 = ci*4 + ky
#define COP     64    // couts padded to 64
#define CT      64    // x-columns per block tile
#define XROWS   70    // CT + KW
#define ROWDW   84    // dwords per XT row = 336 B (21 dwords, odd -> conflict-free b128)
#define TILEDW  (XROWS * ROWDW)   // 5880 dwords = 23.52 KB per y-tile

typedef __attribute__((ext_vector_type(8))) short  short8v;
typedef __attribute__((ext_vector_type(4))) float  float4v;

__device__ __forceinline__ unsigned short f2bf(float f) {
    unsigned u = __float_as_uint(f);
    u += 0x7FFFu + ((u >> 16) & 1u);          // RTNE
    return (unsigned short)(u >> 16);
}

// W2[kx][co(64)][k2(160)] bf16, zero-padded co>=50
__global__ __launch_bounds__(256) void w2_kernel(const float* __restrict__ w,
                                                 unsigned short* __restrict__ w2) {
    unsigned idx = blockIdx.x * 256u + threadIdx.x;
    if (idx >= 6u * COP * K2) return;
    unsigned k2 = idx % K2;
    unsigned tmp = idx / K2;
    unsigned co = tmp % COP;
    unsigned kx = tmp / COP;
    float v = 0.f;
    if (co < COUT) {
        unsigned ci = k2 >> 2, ky = k2 & 3u;
        v = w[co * 960u + ci * 24u + ky * 6u + kx];   // W[co][ci][ky][kx]
    }
    w2[idx] = f2bf(v);
}

// Block: (xtile, ytile(2 rows), t). 4 waves = 2(m-half) x 2(y).
// Wave computes 32co x 64x at one y. K=960 as 6 shifted GEMMs (kx) of K2=160.
__global__ __launch_bounds__(256, 3) void conv_mfma(const float* __restrict__ x,
                                                    const unsigned short* __restrict__ w2,
                                                    float* __restrict__ out) {
    __shared__ unsigned lds[2 * TILEDW];   // 47040 B: two y-tiles XT[c][k2]
    const unsigned xt = blockIdx.x, yt = blockIdx.y, t = blockIdx.z;
    const unsigned y0 = yt * 2u;
    const unsigned tid = threadIdx.x, wave = tid >> 6, lane = tid & 63u;
    const unsigned xbase = xt * CT;
    const unsigned lo = lane & 15u, hi = lane >> 4;

    // ---- stage both XT tiles: unit = (dy, kc): 8 coalesced row loads ->
    //      pack 8 bf16 (x is exactly 0.0/1.0, truncation exact) -> 1 b128 write
    for (unsigned id = wave; id < 40u; id += 4u) {
        unsigned dy = id & 1u, kc = id >> 1;          // k2 chunk = [8kc, 8kc+8)
        unsigned dw0[4], dw1[4];
        #pragma unroll
        for (int j = 0; j < 8; ++j) {
            unsigned ci = 2u * kc + (unsigned)(j >> 2);
            unsigned ky = (unsigned)j & 3u;
            unsigned yr = y0 + dy + ky; if (yr > 159u) yr = 159u;   // clamp (stores masked)
            const float* row = x + (((t * CIN) + ci) * H_IN + yr) * W_IN;
            float v0 = (xbase + lane < W_IN) ? row[xbase + lane] : 0.f;
            float v1 = 0.f;
            if (lane < (XROWS - CT))
                v1 = (xbase + CT + lane < W_IN) ? row[xbase + CT + lane] : 0.f;
            unsigned h0 = __float_as_uint(v0) >> 16;
            unsigned h1 = __float_as_uint(v1) >> 16;
            if (j & 1) { dw0[j >> 1] |= h0 << 16; dw1[j >> 1] |= h1 << 16; }
            else       { dw0[j >> 1]  = h0;       dw1[j >> 1]  = h1;      }
        }
        unsigned base = dy * TILEDW + kc * 4u;
        *reinterpret_cast<uint4*>(&lds[base + lane * ROWDW]) =
            make_uint4(dw0[0], dw0[1], dw0[2], dw0[3]);
        if (lane < (XROWS - CT))
            *reinterpret_cast<uint4*>(&lds[base + (CT + lane) * ROWDW]) =
                make_uint4(dw1[0], dw1[1], dw1[2], dw1[3]);
    }
    __syncthreads();

    const unsigned mh = wave & 1u, yh = wave >> 1;
    const unsigned m0 = mh * 32u;
    const unsigned* tile = lds + yh * TILEDW;

    float4v acc[2][4];
    #pragma unroll
    for (int mf = 0; mf < 2; ++mf)
        #pragma unroll
        for (int nt = 0; nt < 4; ++nt) acc[mf][nt] = (float4v){0.f, 0.f, 0.f, 0.f};

    for (unsigned kx = 0; kx < 6u; ++kx) {
        short8v a[2][5];
        const unsigned short* wb = w2 + (kx * COP + m0 + lo) * K2 + 8u * hi;
        #pragma unroll
        for (int mf = 0; mf < 2; ++mf)
            #pragma unroll
            for (int ks = 0; ks < 5; ++ks)
                a[mf][ks] = *reinterpret_cast<const short8v*>(wb + mf * 16 * K2 + ks * 32);
        #pragma unroll
        for (int nt = 0; nt < 4; ++nt) {
            const unsigned* bp = tile + (nt * 16u + lo + kx) * ROWDW + 4u * hi;
            #pragma unroll
            for (int ks = 0; ks < 5; ++ks) {
                short8v b = *reinterpret_cast<const short8v*>(bp + 16 * ks);
                acc[0][nt] = __builtin_amdgcn_mfma_f32_16x16x32_bf16(a[0][ks], b, acc[0][nt], 0, 0, 0);
                acc[1][nt] = __builtin_amdgcn_mfma_f32_16x16x32_bf16(a[1][ks], b, acc[1][nt], 0, 0, 0);
            }
        }
    }

    // ---- epilogue: co = m0 + mf*16 + 4*hi + r, x = xbase + nt*16 + lo ----
    const unsigned y = y0 + yh;
    if (y < OH) {
        #pragma unroll
        for (int nt = 0; nt < 4; ++nt) {
            unsigned xcol = xbase + nt * 16u + lo;
            if (xcol >= OW) continue;
            #pragma unroll
            for (int mf = 0; mf < 2; ++mf) {
                #pragma unroll
                for (int r = 0; r < 4; ++r) {
                    unsigned co = m0 + mf * 16u + 4u * hi + (unsigned)r;
                    if (co < COUT)
                        out[1 + ((((t * COUT) + co) * OH + y) * OW + xcol)] = acc[mf][nt][r];
                }
            }
        }
    }
}

// Per-block partial min over pooled spike indices (no contended atomics).
__global__ __launch_bounds__(256) void scan_kernel(const float* __restrict__ out,
                                                   unsigned* __restrict__ parts) {
    __shared__ unsigned sm[4];
    unsigned tid = threadIdx.x;
    unsigned idx = blockIdx.x * 256u + tid;
    unsigned cand = ~0u;
    const unsigned TOT = COUT * PH * PW;
    if (idx < TOT) {
        unsigned c   = idx / (PH * PW);
        unsigned rem = idx % (PH * PW);
        unsigned pi  = rem / PW;
        unsigned pj  = rem % PW;
        const float* base = out + 1
            + ((((T_STEPS - 1) * COUT) + c) * OH + 3 * pi) * OW + 3 * pj;
        bool spike = false;
        #pragma unroll
        for (int r = 0; r < 3; ++r)
            #pragma unroll
            for (int s = 0; s < 3; ++s)
                spike = spike || (base[r * OW + s] >= THRESH);
        if (spike) cand = idx;
    }
    #pragma unroll
    for (int off = 32; off > 0; off >>= 1) {
        unsigned o = __shfl_down(cand, off, 64);
        cand = cand < o ? cand : o;
    }
    if ((tid & 63u) == 0u) sm[tid >> 6] = cand;
    __syncthreads();
    if (tid == 0u) {
        unsigned m = sm[0];
        #pragma unroll
        for (int i = 1; i < 4; ++i) m = m < sm[i] ? m : sm[i];
        parts[blockIdx.x] = m;
    }
}

// Final reduce of 996 partials -> decision scalar at out[0].
__global__ void fin_kernel(const unsigned* __restrict__ parts, int nparts,
                           float* __restrict__ out) {
    __shared__ unsigned sm[16];
    unsigned tid = threadIdx.x;
    unsigned m = (tid < (unsigned)nparts) ? parts[tid] : ~0u;
    #pragma unroll
    for (int off = 32; off > 0; off >>= 1) {
        unsigned o = __shfl_down(m, off, 64);
        m = m < o ? m : o;
    }
    if ((tid & 63u) == 0u) sm[tid >> 6] = m;
    __syncthreads();
    if (tid == 0u) {
        unsigned mm = sm[0];
        #pragma unroll
        for (int i = 1; i < 16; ++i) mm = mm < sm[i] ? mm : sm[i];
        int dec = (mm == ~0u) ? -1 : (int)((mm / (PH * PW)) / 20u);
        out[0] = (float)dec;
    }
}

extern "C" void kernel_launch(void* const* d_in, const int* in_sizes, int n_in,
                              void* d_out, int out_size, void* d_ws, size_t ws_size,
                              hipStream_t stream) {
    const float* x = (const float*)d_in[0];
    const float* w = (const float*)d_in[1];
    float* out     = (float*)d_out;
    unsigned short* w2 = (unsigned short*)d_ws;                        // 122880 B
    unsigned* parts    = (unsigned*)((char*)d_ws + 131072);            // 996 dwords

    hipLaunchKernelGGL(w2_kernel, dim3((6u * COP * K2 + 255u) / 256u), dim3(256),
                       0, stream, w, w2);

    hipLaunchKernelGGL(conv_mfma, dim3(5, 79, 15), dim3(256), 0, stream,
                       x, w2, out);

    const unsigned TOT = COUT * PH * PW;                // 254800
    const unsigned nblk = (TOT + 255u) / 256u;          // 996
    hipLaunchKernelGGL(scan_kernel, dim3(nblk), dim3(256), 0, stream, out, parts);

    hipLaunchKernelGGL(fin_kernel, dim3(1), dim3(1024), 0, stream,
                       parts, (int)nblk, out);
}

// Round 4
// 524.099 us; speedup vs baseline: 1.2995x; 1.2995x over previous
//
#include <hip/hip_runtime.h>
#include <hip/hip_bf16.h>

#define T_STEPS 15
#define CIN     40
#define H_IN    160
#define W_IN    300
#define COUT    50
#define OH      157   // 160-4+1
#define OW      295   // 300-6+1
#define PH      52
#define PW      98
#define THRESH  15.0f

#define TSTRIDE (H_IN * W_IN * CIN)   // 1,920,000 bf16 elems per t in XTc

typedef __attribute__((ext_vector_type(8))) short  short8v;
typedef __attribute__((ext_vector_type(4))) float  float4v;

__device__ __forceinline__ unsigned short f2bf(float f) {
    unsigned u = __float_as_uint(f);
    u += 0x7FFFu + ((u >> 16) & 1u);          // RTNE
    return (unsigned short)(u >> 16);
}

// w2A[kx][ks][mf][lane][j]: A-frag for mfma_16x16x32, k-slot (hi,j) = (ky=hi, ci=ks*8+j).
// value = W[co = mf*16 + (lane&15)][ci][ky][kx], zero-padded co>=50. 61440 elems.
__global__ __launch_bounds__(256) void w2a_kernel(const float* __restrict__ w,
                                                  unsigned short* __restrict__ w2a) {
    unsigned idx = blockIdx.x * 256u + threadIdx.x;
    if (idx >= 61440u) return;
    unsigned j    = idx & 7u;
    unsigned tmp  = idx >> 3;
    unsigned lane = tmp & 63u; tmp >>= 6;
    unsigned mf   = tmp & 3u;  tmp >>= 2;
    unsigned ks   = tmp % 5u, kx = tmp / 5u;
    unsigned co = mf * 16u + (lane & 15u);
    unsigned ky = lane >> 4;
    unsigned ci = ks * 8u + j;
    float v = (co < COUT) ? w[co * 960u + ci * 24u + ky * 6u + kx] : 0.f;
    w2a[idx] = f2bf(v);
}

// Transpose prepass: XTc[t][yy][xc][ci] = bf16(x[t][ci][yy][xc]).
// Block (xcb, yy, tz): 64 xc cols x 40 ci through an LDS tile.
__global__ __launch_bounds__(256) void pre_kernel(const float* __restrict__ x,
                                                  unsigned short* __restrict__ xtc,
                                                  unsigned t0, unsigned otstride) {
    __shared__ unsigned short tl[CIN][66];
    unsigned xcb = blockIdx.x, yy = blockIdx.y, tz = blockIdx.z;
    unsigned t = t0 + tz;
    unsigned tid = threadIdx.x, lane = tid & 63u, wv = tid >> 6;
    unsigned xc0 = xcb * 64u;
    unsigned ncols = (W_IN - xc0 < 64u) ? (W_IN - xc0) : 64u;   // 64 or 44
    for (unsigned ci = wv; ci < CIN; ci += 4u) {
        float v = 0.f;
        if (lane < ncols) v = x[((size_t)(t * CIN + ci) * H_IN + yy) * W_IN + xc0 + lane];
        tl[ci][lane] = f2bf(v);   // x is exactly 0/1
    }
    __syncthreads();
    unsigned total = ncols * 20u;                       // dwords (40 bf16 per xc)
    unsigned* outp = (unsigned*)(xtc + (size_t)tz * otstride
                                 + ((size_t)yy * W_IN + xc0) * CIN);
    for (unsigned g = tid; g < total; g += 256u) {
        unsigned xc = g / 20u, cd = g % 20u;
        unsigned lo16 = tl[2u * cd][xc], hi16 = tl[2u * cd + 1u][xc];
        outp[g] = lo16 | (hi16 << 16);
    }
}

// No-LDS implicit-GEMM conv: 1 wave = 64co x 64xc at one (t,y).
// B-frags stream from XTc (16B/lane, L1-resident window), A-frags from w2A.
__global__ __launch_bounds__(256) void conv_mfma(const unsigned short* __restrict__ xtc,
                                                 const unsigned short* __restrict__ w2a,
                                                 float* __restrict__ out,
                                                 unsigned t0, unsigned tstride,
                                                 unsigned ntiles) {
    unsigned gw = blockIdx.x * 4u + (threadIdx.x >> 6);
    if (gw >= ntiles) return;
    unsigned lane = threadIdx.x & 63u;
    unsigned tl = gw / 785u, rem = gw % 785u;     // 785 = 157y * 5xt
    unsigned y = rem / 5u, xt = rem % 5u;
    unsigned t = t0 + tl;
    unsigned lo = lane & 15u, hi = lane >> 4;
    unsigned n0 = xt * 64u;

    // lane's B row pointer: row yy = y + hi (= ky), col n0 + lo, ci-contig
    const unsigned short* rp = xtc + (size_t)tl * tstride
                             + ((size_t)(y + hi) * W_IN + n0 + lo) * CIN;

    float4v acc[4][4];
    #pragma unroll
    for (int mf = 0; mf < 4; ++mf)
        #pragma unroll
        for (int nt = 0; nt < 4; ++nt) acc[mf][nt] = (float4v){0.f, 0.f, 0.f, 0.f};

    for (unsigned kx = 0; kx < 6u; ++kx) {
        const unsigned short* wb = w2a + kx * 20u * 512u + lane * 8u;
        const unsigned short* bp = rp + kx * CIN;
        #pragma unroll
        for (unsigned ks = 0; ks < 5u; ++ks) {
            short8v a[4], b[4];
            #pragma unroll
            for (int mf = 0; mf < 4; ++mf)
                a[mf] = *reinterpret_cast<const short8v*>(wb + (ks * 4u + mf) * 512u);
            #pragma unroll
            for (int nt = 0; nt < 4; ++nt)
                b[nt] = *reinterpret_cast<const short8v*>(bp + nt * 16u * CIN + ks * 8u);
            #pragma unroll
            for (int nt = 0; nt < 4; ++nt)
                #pragma unroll
                for (int mf = 0; mf < 4; ++mf)
                    acc[mf][nt] = __builtin_amdgcn_mfma_f32_16x16x32_bf16(
                        a[mf], b[nt], acc[mf][nt], 0, 0, 0);
        }
    }

    // epilogue: co = mf*16 + 4*hi + r, xcol = n0 + nt*16 + lo
    #pragma unroll
    for (int nt = 0; nt < 4; ++nt) {
        unsigned xcol = n0 + (unsigned)nt * 16u + lo;
        if (xcol >= OW) continue;
        #pragma unroll
        for (int mf = 0; mf < 4; ++mf) {
            #pragma unroll
            for (int r = 0; r < 4; ++r) {
                unsigned co = (unsigned)mf * 16u + 4u * hi + (unsigned)r;
                if (co < COUT)
                    out[1 + ((((size_t)t * COUT + co) * OH + y) * OW + xcol)] = acc[mf][nt][r];
            }
        }
    }
}

// Per-block partial min over pooled spike indices (t=14 slice).
__global__ __launch_bounds__(256) void scan_kernel(const float* __restrict__ out,
                                                   unsigned* __restrict__ parts) {
    __shared__ unsigned sm[4];
    unsigned tid = threadIdx.x;
    unsigned idx = blockIdx.x * 256u + tid;
    unsigned cand = ~0u;
    const unsigned TOT = COUT * PH * PW;
    if (idx < TOT) {
        unsigned c   = idx / (PH * PW);
        unsigned rem = idx % (PH * PW);
        unsigned pi  = rem / PW;
        unsigned pj  = rem % PW;
        const float* base = out + 1
            + ((((T_STEPS - 1) * COUT) + c) * OH + 3 * pi) * OW + 3 * pj;
        bool spike = false;
        #pragma unroll
        for (int r = 0; r < 3; ++r)
            #pragma unroll
            for (int s = 0; s < 3; ++s)
                spike = spike || (base[r * OW + s] >= THRESH);
        if (spike) cand = idx;
    }
    #pragma unroll
    for (int off = 32; off > 0; off >>= 1) {
        unsigned o = __shfl_down(cand, off, 64);
        cand = cand < o ? cand : o;
    }
    if ((tid & 63u) == 0u) sm[tid >> 6] = cand;
    __syncthreads();
    if (tid == 0u) {
        unsigned m = sm[0];
        #pragma unroll
        for (int i = 1; i < 4; ++i) m = m < sm[i] ? m : sm[i];
        parts[blockIdx.x] = m;
    }
}

__global__ void fin_kernel(const unsigned* __restrict__ parts, int nparts,
                           float* __restrict__ out) {
    __shared__ unsigned sm[16];
    unsigned tid = threadIdx.x;
    unsigned m = (tid < (unsigned)nparts) ? parts[tid] : ~0u;
    #pragma unroll
    for (int off = 32; off > 0; off >>= 1) {
        unsigned o = __shfl_down(m, off, 64);
        m = m < o ? m : o;
    }
    if ((tid & 63u) == 0u) sm[tid >> 6] = m;
    __syncthreads();
    if (tid == 0u) {
        unsigned mm = sm[0];
        #pragma unroll
        for (int i = 1; i < 16; ++i) mm = mm < sm[i] ? mm : sm[i];
        int dec = (mm == ~0u) ? -1 : (int)((mm / (PH * PW)) / 20u);
        out[0] = (float)dec;
    }
}

extern "C" void kernel_launch(void* const* d_in, const int* in_sizes, int n_in,
                              void* d_out, int out_size, void* d_ws, size_t ws_size,
                              hipStream_t stream) {
    const float* x = (const float*)d_in[0];
    const float* w = (const float*)d_in[1];
    float* out     = (float*)d_out;
    unsigned short* w2a = (unsigned short*)d_ws;                    // 122880 B
    unsigned* parts     = (unsigned*)((char*)d_ws + 122880);        // 996 dwords
    unsigned short* xtc = (unsigned short*)((char*)d_ws + 131072);

    const size_t needA = 131072ull + (size_t)15 * TSTRIDE * 2 + 8192;   // ~57.7 MB
    const bool planA = (ws_size >= needA);

    hipLaunchKernelGGL(w2a_kernel, dim3(240), dim3(256), 0, stream, w, w2a);

    if (planA) {
        hipLaunchKernelGGL(pre_kernel, dim3(5, 160, 15), dim3(256), 0, stream,
                           x, xtc, 0u, (unsigned)TSTRIDE);
        const unsigned ntiles = 15u * 785u;                          // 11775
        hipLaunchKernelGGL(conv_mfma, dim3((ntiles + 3u) / 4u), dim3(256), 0, stream,
                           xtc, w2a, out, 0u, (unsigned)TSTRIDE, ntiles);
    } else {
        for (unsigned t = 0; t < 15u; ++t) {
            hipLaunchKernelGGL(pre_kernel, dim3(5, 160, 1), dim3(256), 0, stream,
                               x, xtc, t, 0u);
            hipLaunchKernelGGL(conv_mfma, dim3(197), dim3(256), 0, stream,
                               xtc, w2a, out, t, 0u, 785u);
        }
    }

    const unsigned TOT = COUT * PH * PW;                 // 254800
    const unsigned nblk = (TOT + 255u) / 256u;           // 996
    hipLaunchKernelGGL(scan_kernel, dim3(nblk), dim3(256), 0, stream, out, parts);
    hipLaunchKernelGGL(fin_kernel, dim3(1), dim3(1024), 0, stream,
                       parts, (int)nblk, out);
}

// Round 5
// 385.691 us; speedup vs baseline: 1.7658x; 1.3589x over previous
//
#include <hip/hip_runtime.h>
#include <hip/hip_bf16.h>

#define T_STEPS 15
#define CIN     40
#define H_IN    160
#define W_IN    300
#define COUT    50
#define OH      157   // 160-4+1
#define OW      295   // 300-6+1
#define PH      52
#define PW      98
#define THRESH  15.0f

#define TSTRIDE (H_IN * W_IN * CIN)   // 1,920,000 bf16 elems per t in XTc

typedef __attribute__((ext_vector_type(8))) short  short8v;
typedef __attribute__((ext_vector_type(4))) float  float4v;

__device__ __forceinline__ unsigned short f2bf(float f) {
    unsigned u = __float_as_uint(f);
    u += 0x7FFFu + ((u >> 16) & 1u);          // RTNE
    return (unsigned short)(u >> 16);
}

// w2A[kx][ks][mf][lane][j]: A-frag for mfma_16x16x32, k-slot (hi,j) = (ky=hi, ci=ks*8+j).
// value = W[co = mf*16 + (lane&15)][ci][ky][kx], zero-padded co>=50. 61440 elems.
__global__ __launch_bounds__(256) void w2a_kernel(const float* __restrict__ w,
                                                  unsigned short* __restrict__ w2a) {
    unsigned idx = blockIdx.x * 256u + threadIdx.x;
    if (idx >= 61440u) return;
    unsigned j    = idx & 7u;
    unsigned tmp  = idx >> 3;
    unsigned lane = tmp & 63u; tmp >>= 6;
    unsigned mf   = tmp & 3u;  tmp >>= 2;
    unsigned ks   = tmp % 5u, kx = tmp / 5u;
    unsigned co = mf * 16u + (lane & 15u);
    unsigned ky = lane >> 4;
    unsigned ci = ks * 8u + j;
    float v = (co < COUT) ? w[co * 960u + ci * 24u + ky * 6u + kx] : 0.f;
    w2a[idx] = f2bf(v);
}

// Transpose prepass: XTc[t][yy][xc][ci] = bf16(x[t][ci][yy][xc]).
// Block = one (t, yy): float4 loads -> LDS (306-short padded rows) -> packed dword stores.
__global__ __launch_bounds__(256) void pre_kernel(const float* __restrict__ x,
                                                  unsigned short* __restrict__ xtc,
                                                  unsigned t0, unsigned otstride) {
    __shared__ unsigned short tl[CIN][306];
    const unsigned yy = blockIdx.x, tz = blockIdx.y;
    const unsigned t = t0 + tz;
    const unsigned tid = threadIdx.x;
    // load 40ci x 300xc as float4 (75 per row), truncate to bf16 (x is exactly 0/1)
    for (unsigned g = tid; g < 3000u; g += 256u) {
        unsigned ci = g / 75u, q = g % 75u;
        float4 v = *reinterpret_cast<const float4*>(
            x + ((size_t)(t * CIN + ci) * H_IN + yy) * W_IN + 4u * q);
        unsigned u0 = (__float_as_uint(v.x) >> 16) | ((__float_as_uint(v.y) >> 16) << 16);
        unsigned u1 = (__float_as_uint(v.z) >> 16) | ((__float_as_uint(v.w) >> 16) << 16);
        unsigned* p = reinterpret_cast<unsigned*>(&tl[ci][4u * q]);
        p[0] = u0; p[1] = u1;
    }
    __syncthreads();
    // emit 6000 dwords: ((yy*300)+xc)*20 + cd ; value = (ci=2cd, 2cd+1) at col xc
    unsigned* outp = reinterpret_cast<unsigned*>(
        xtc + (size_t)tz * otstride + (size_t)yy * W_IN * CIN);
    for (unsigned g = tid; g < 6000u; g += 256u) {
        unsigned xc = g / 20u, cd = g % 20u;
        unsigned lo16 = tl[2u * cd][xc], hi16 = tl[2u * cd + 1u][xc];
        outp[g] = lo16 | (hi16 << 16);
    }
}

// No-LDS implicit-GEMM conv. Block = (t, xt, yb): 4 waves = 4 consecutive y-pairs.
// Wave tile: 64co x 64xc x 2y. B streams from XTc (L1/L2-hot window), A from w2A.
// Bijective XCD swizzle: consecutive blocks on one XCD walk y within a strip.
__global__ __launch_bounds__(256, 2) void conv_mfma(const unsigned short* __restrict__ xtc,
                                                    const unsigned short* __restrict__ w2a,
                                                    float* __restrict__ out,
                                                    unsigned t0, unsigned tstride,
                                                    unsigned nb) {
    // --- XCD-bijective block remap ---
    unsigned orig = blockIdx.x;
    unsigned q = nb / 8u, r = nb % 8u;
    unsigned xcd = orig & 7u, i = orig >> 3;
    unsigned swz = (xcd < r) ? xcd * (q + 1u) + i
                             : r * (q + 1u) + (xcd - r) * q + i;
    // strip-major decode: swz = ((tloc*5)+xt)*20 + yb
    unsigned st = swz / 20u, yb = swz % 20u;
    unsigned tloc = st / 5u, xt = st % 5u;
    unsigned t = t0 + tloc;

    const unsigned wv = threadIdx.x >> 6, lane = threadIdx.x & 63u;
    const unsigned lo = lane & 15u, hi = lane >> 4;
    const unsigned n0 = xt * 64u;
    const unsigned y0 = yb * 8u + wv * 2u;          // wave handles y0, y0+1

    unsigned yr0 = y0 + hi;       if (yr0 > 159u) yr0 = 159u;   // stores masked
    unsigned yr1 = y0 + 1u + hi;  if (yr1 > 159u) yr1 = 159u;

    const unsigned short* rp0 = xtc + (size_t)tloc * tstride
                              + ((size_t)yr0 * W_IN + n0 + lo) * CIN;
    const unsigned short* rp1 = xtc + (size_t)tloc * tstride
                              + ((size_t)yr1 * W_IN + n0 + lo) * CIN;

    float4v acc[4][4][2];
    #pragma unroll
    for (int mf = 0; mf < 4; ++mf)
        #pragma unroll
        for (int nt = 0; nt < 4; ++nt)
            #pragma unroll
            for (int yyp = 0; yyp < 2; ++yyp)
                acc[mf][nt][yyp] = (float4v){0.f, 0.f, 0.f, 0.f};

    for (unsigned kx = 0; kx < 6u; ++kx) {
        const unsigned short* wb  = w2a + kx * 20u * 512u + lane * 8u;
        const unsigned short* bp0 = rp0 + kx * CIN;
        const unsigned short* bp1 = rp1 + kx * CIN;
        #pragma unroll
        for (unsigned ks = 0; ks < 5u; ++ks) {
            short8v a[4], b[4][2];
            #pragma unroll
            for (int mf = 0; mf < 4; ++mf)
                a[mf] = *reinterpret_cast<const short8v*>(wb + (ks * 4u + mf) * 512u);
            #pragma unroll
            for (int nt = 0; nt < 4; ++nt) {
                b[nt][0] = *reinterpret_cast<const short8v*>(bp0 + nt * 16u * CIN + ks * 8u);
                b[nt][1] = *reinterpret_cast<const short8v*>(bp1 + nt * 16u * CIN + ks * 8u);
            }
            #pragma unroll
            for (int nt = 0; nt < 4; ++nt)
                #pragma unroll
                for (int mf = 0; mf < 4; ++mf) {
                    acc[mf][nt][0] = __builtin_amdgcn_mfma_f32_16x16x32_bf16(
                        a[mf], b[nt][0], acc[mf][nt][0], 0, 0, 0);
                    acc[mf][nt][1] = __builtin_amdgcn_mfma_f32_16x16x32_bf16(
                        a[mf], b[nt][1], acc[mf][nt][1], 0, 0, 0);
                }
        }
    }

    // epilogue: co = mf*16 + 4*hi + rr, xcol = n0 + nt*16 + lo, y = y0 + yyp
    #pragma unroll
    for (int yyp = 0; yyp < 2; ++yyp) {
        unsigned y = y0 + (unsigned)yyp;
        if (y >= OH) continue;
        #pragma unroll
        for (int nt = 0; nt < 4; ++nt) {
            unsigned xcol = n0 + (unsigned)nt * 16u + lo;
            if (xcol >= OW) continue;
            #pragma unroll
            for (int mf = 0; mf < 4; ++mf) {
                #pragma unroll
                for (int rr = 0; rr < 4; ++rr) {
                    unsigned co = (unsigned)mf * 16u + 4u * hi + (unsigned)rr;
                    if (co < COUT)
                        out[1 + ((((size_t)t * COUT + co) * OH + y) * OW + xcol)]
                            = acc[mf][nt][yyp][rr];
                }
            }
        }
    }
}

// Per-block partial min over pooled spike indices (t=14 slice).
__global__ __launch_bounds__(256) void scan_kernel(const float* __restrict__ out,
                                                   unsigned* __restrict__ parts) {
    __shared__ unsigned sm[4];
    unsigned tid = threadIdx.x;
    unsigned idx = blockIdx.x * 256u + tid;
    unsigned cand = ~0u;
    const unsigned TOT = COUT * PH * PW;
    if (idx < TOT) {
        unsigned c   = idx / (PH * PW);
        unsigned rem = idx % (PH * PW);
        unsigned pi  = rem / PW;
        unsigned pj  = rem % PW;
        const float* base = out + 1
            + ((((T_STEPS - 1) * COUT) + c) * OH + 3 * pi) * OW + 3 * pj;
        bool spike = false;
        #pragma unroll
        for (int rr = 0; rr < 3; ++rr)
            #pragma unroll
            for (int s = 0; s < 3; ++s)
                spike = spike || (base[rr * OW + s] >= THRESH);
        if (spike) cand = idx;
    }
    #pragma unroll
    for (int off = 32; off > 0; off >>= 1) {
        unsigned o = __shfl_down(cand, off, 64);
        cand = cand < o ? cand : o;
    }
    if ((tid & 63u) == 0u) sm[tid >> 6] = cand;
    __syncthreads();
    if (tid == 0u) {
        unsigned m = sm[0];
        #pragma unroll
        for (int i = 1; i < 4; ++i) m = m < sm[i] ? m : sm[i];
        parts[blockIdx.x] = m;
    }
}

__global__ void fin_kernel(const unsigned* __restrict__ parts, int nparts,
                           float* __restrict__ out) {
    __shared__ unsigned sm[16];
    unsigned tid = threadIdx.x;
    unsigned m = (tid < (unsigned)nparts) ? parts[tid] : ~0u;
    #pragma unroll
    for (int off = 32; off > 0; off >>= 1) {
        unsigned o = __shfl_down(m, off, 64);
        m = m < o ? m : o;
    }
    if ((tid & 63u) == 0u) sm[tid >> 6] = m;
    __syncthreads();
    if (tid == 0u) {
        unsigned mm = sm[0];
        #pragma unroll
        for (int i = 1; i < 16; ++i) mm = mm < sm[i] ? mm : sm[i];
        int dec = (mm == ~0u) ? -1 : (int)((mm / (PH * PW)) / 20u);
        out[0] = (float)dec;
    }
}

extern "C" void kernel_launch(void* const* d_in, const int* in_sizes, int n_in,
                              void* d_out, int out_size, void* d_ws, size_t ws_size,
                              hipStream_t stream) {
    const float* x = (const float*)d_in[0];
    const float* w = (const float*)d_in[1];
    float* out     = (float*)d_out;
    unsigned short* w2a = (unsigned short*)d_ws;                    // 122880 B
    unsigned* parts     = (unsigned*)((char*)d_ws + 122880);        // 996 dwords
    unsigned short* xtc = (unsigned short*)((char*)d_ws + 131072);

    const size_t needA = 131072ull + (size_t)15 * TSTRIDE * 2 + 8192;   // ~57.7 MB
    const bool planA = (ws_size >= needA);

    hipLaunchKernelGGL(w2a_kernel, dim3(240), dim3(256), 0, stream, w, w2a);

    if (planA) {
        hipLaunchKernelGGL(pre_kernel, dim3(160, 15), dim3(256), 0, stream,
                           x, xtc, 0u, (unsigned)TSTRIDE);
        const unsigned nb = 15u * 5u * 20u;                          // 1500
        hipLaunchKernelGGL(conv_mfma, dim3(nb), dim3(256), 0, stream,
                           xtc, w2a, out, 0u, (unsigned)TSTRIDE, nb);
    } else {
        for (unsigned t = 0; t < 15u; ++t) {
            hipLaunchKernelGGL(pre_kernel, dim3(160, 1), dim3(256), 0, stream,
                               x, xtc, t, 0u);
            hipLaunchKernelGGL(conv_mfma, dim3(100), dim3(256), 0, stream,
                               xtc, w2a, out, t, 0u, 100u);
        }
    }

    const unsigned TOT = COUT * PH * PW;                 // 254800
    const unsigned nblk = (TOT + 255u) / 256u;           // 996
    hipLaunchKernelGGL(scan_kernel, dim3(nblk), dim3(256), 0, stream, out, parts);
    hipLaunchKernelGGL(fin_kernel, dim3(1), dim3(1024), 0, stream,
                       parts, (int)nblk, out);
}